// Round 1
// baseline (376.020 us; speedup 1.0000x reference)
//
#include <hip/hip_runtime.h>
#include <hip/hip_bf16.h>

#define T_SEQ 2048
#define BATCH 4
#define NH    16
#define DM    1024
#define HD    64

typedef __attribute__((ext_vector_type(4))) float  f32x4;
typedef __attribute__((ext_vector_type(8))) short  s16x8;
typedef __attribute__((ext_vector_type(4))) short  s16x4;

__device__ __forceinline__ unsigned short f2b(float f) {
  union { float f; unsigned u; } v; v.f = f;
  unsigned u = v.u;
  unsigned r = 0x7fffu + ((u >> 16) & 1u);
  u += r;
  return (unsigned short)(u >> 16);
}

__device__ __forceinline__ f32x4 mfma16(s16x8 a, s16x8 b, f32x4 c) {
  return __builtin_amdgcn_mfma_f32_16x16x32_bf16(a, b, c, 0, 0, 0);
}

// ---------------- fp32 -> bf16 convert (vectorized) ----------------
__global__ void cvt_f32_bf16(const float* __restrict__ src,
                             unsigned short* __restrict__ dst, int n4) {
  int i = blockIdx.x * blockDim.x + threadIdx.x;
  int stride = gridDim.x * blockDim.x;
  for (int j = i; j < n4; j += stride) {
    f32x4 v = ((const f32x4*)src)[j];
    s16x4 o;
    o.x = (short)f2b(v.x); o.y = (short)f2b(v.y);
    o.z = (short)f2b(v.z); o.w = (short)f2b(v.w);
    ((s16x4*)dst)[j] = o;
  }
}

// ---------------- GEMM: C[M,N] = A[M,K] * B[N,K]^T  (bf16 in, bf16/f32 out) ----------------
template<int OUT_F32>
__global__ __launch_bounds__(256)
void gemm_bt(const unsigned short* __restrict__ A,
             const unsigned short* __restrict__ B,
             void* __restrict__ C, int M, int N, int K) {
  __shared__ unsigned short As[128 * 40];   // stride 40 elems = 80B (conflict-free b128 reads)
  __shared__ unsigned short Bs[128 * 40];
  const int tid  = threadIdx.x;
  const int lane = tid & 63;
  const int w    = tid >> 6;
  const int wr   = w >> 1, wc = w & 1;
  const int lr   = lane & 15, g = lane >> 4;
  const int row0 = blockIdx.x * 128;
  const int col0 = blockIdx.y * 128;

  f32x4 acc[4][4] = {};

  for (int kt = 0; kt < K; kt += 32) {
    __syncthreads();
#pragma unroll
    for (int s = 0; s < 2; ++s) {
      int c = tid + s * 256;            // 512 chunks of 8 elems
      int r = c >> 2, k0 = (c & 3) * 8;
      *(s16x8*)&As[r * 40 + k0] =
        *(const s16x8*)&A[(size_t)(row0 + r) * K + kt + k0];
      *(s16x8*)&Bs[r * 40 + k0] =
        *(const s16x8*)&B[(size_t)(col0 + r) * K + kt + k0];
    }
    __syncthreads();
    s16x8 af[4], bf[4];
#pragma unroll
    for (int m = 0; m < 4; ++m)
      af[m] = *(const s16x8*)&As[(wr * 64 + m * 16 + lr) * 40 + g * 8];
#pragma unroll
    for (int n = 0; n < 4; ++n)
      bf[n] = *(const s16x8*)&Bs[(wc * 64 + n * 16 + lr) * 40 + g * 8];
#pragma unroll
    for (int m = 0; m < 4; ++m)
#pragma unroll
      for (int n = 0; n < 4; ++n)
        acc[m][n] = mfma16(af[m], bf[n], acc[m][n]);
  }

#pragma unroll
  for (int m = 0; m < 4; ++m)
#pragma unroll
    for (int n = 0; n < 4; ++n)
#pragma unroll
      for (int i = 0; i < 4; ++i) {
        int row = row0 + wr * 64 + m * 16 + g * 4 + i;
        int col = col0 + wc * 64 + n * 16 + lr;
        if (OUT_F32)
          ((float*)C)[(size_t)row * N + col] = acc[m][n][i];
        else
          ((unsigned short*)C)[(size_t)row * N + col] = f2b(acc[m][n][i]);
      }
}

// ---------------- causal flash attention ----------------
// qkv layout: [B*T, 3072], feature col = f*1024 + h*64 + d
// out: bf16 [B*T, 1024], col = h*64 + d
__global__ __launch_bounds__(256)
void attn_kernel(const unsigned short* __restrict__ qkv,
                 unsigned short* __restrict__ out) {
  __shared__ unsigned short Ks[64 * 72];      // [key][d], stride 72
  __shared__ unsigned short Vt[64 * 72];      // [d][key] transposed + byte-swizzled
  __shared__ unsigned short Ps[4][16 * 72];   // per-wave P, [qrow][key], stride 72

  const int tid  = threadIdx.x;
  const int lane = tid & 63;
  const int w    = tid >> 6;
  const int lr   = lane & 15, g = lane >> 4;
  const int qt   = blockIdx.x;          // q-tile 0..31
  const int bh   = blockIdx.y;          // 0..63
  const int b    = bh >> 4, h = bh & 15;
  const int q0   = qt * 64;
  const int qr   = q0 + w * 16;         // this wave's first q row
  const size_t rb = (size_t)b * T_SEQ;  // row base

  // Q fragments (A-operand), direct from global: Q[qr+lr][g*8..+7] per d-chunk
  s16x8 qf[2];
  {
    const unsigned short* qp = qkv + (rb + qr + lr) * 3072 + h * 64;
    qf[0] = *(const s16x8*)(qp + g * 8);
    qf[1] = *(const s16x8*)(qp + 32 + g * 8);
  }

  float mI[4], lI[4];
  f32x4 o[4] = {};
#pragma unroll
  for (int i = 0; i < 4; ++i) { mI[i] = -1e30f; lI[i] = 0.f; }

  const int ntiles = qt + 1;
  for (int t = 0; t < ntiles; ++t) {
    const int kv0 = t * 64;
    __syncthreads();   // protect LDS from previous iteration's readers
    // ---- stage K linear [key][d] ----
#pragma unroll
    for (int s = 0; s < 2; ++s) {
      int c = tid + s * 256;
      int r = c >> 3, d0 = (c & 7) * 8;
      *(s16x8*)&Ks[r * 72 + d0] =
        *(const s16x8*)&qkv[(rb + kv0 + r) * 3072 + 1024 + h * 64 + d0];
    }
    // ---- stage V transposed: Vt[d][key], pair of rows packed into u32 writes ----
    {
      int rp = tid >> 3, d0 = (tid & 7) * 8;
      int r0 = rp * 2;
      const unsigned short* vp = &qkv[(rb + kv0 + r0) * 3072 + 2048 + h * 64 + d0];
      s16x8 v0 = *(const s16x8*)vp;
      s16x8 v1 = *(const s16x8*)(vp + 3072);
#pragma unroll
      for (int jj = 0; jj < 8; ++jj) {
        int d = d0 + jj;
        int sw = ((d ^ (d >> 3)) & 7) << 4;   // byte-level XOR swizzle (16B granules)
        unsigned val = (unsigned)(unsigned short)v0[jj] |
                       ((unsigned)(unsigned short)v1[jj] << 16);
        *(unsigned*)((char*)Vt + d * 144 + ((r0 * 2) ^ sw)) = val;
      }
    }
    __syncthreads();

    // ---- S = Q K^T (4 key-frags of 16) ----
    f32x4 s4[4];
#pragma unroll
    for (int kc = 0; kc < 4; ++kc) {
      s16x8 kf0 = *(const s16x8*)&Ks[(kc * 16 + lr) * 72 + g * 8];
      s16x8 kf1 = *(const s16x8*)&Ks[(kc * 16 + lr) * 72 + 32 + g * 8];
      f32x4 s = {};
      s = mfma16(qf[0], kf0, s);
      s = mfma16(qf[1], kf1, s);
      s4[kc] = s;
    }

    // ---- scale + causal mask ----
#pragma unroll
    for (int kc = 0; kc < 4; ++kc) {
      int key = kv0 + kc * 16 + lr;
#pragma unroll
      for (int i = 0; i < 4; ++i) {
        int qrow = qr + g * 4 + i;
        float v = s4[kc][i] * 0.125f;
        s4[kc][i] = (key <= qrow) ? v : -1e30f;
      }
    }

    // ---- online softmax (row reduce across the 16-lane group) ----
    float alpha[4];
#pragma unroll
    for (int i = 0; i < 4; ++i) {
      float mx = fmaxf(fmaxf(s4[0][i], s4[1][i]), fmaxf(s4[2][i], s4[3][i]));
#pragma unroll
      for (int dd = 1; dd < 16; dd <<= 1)
        mx = fmaxf(mx, __shfl_xor(mx, dd, 64));
      float mn = fmaxf(mI[i], mx);
      alpha[i] = __expf(mI[i] - mn);
      mI[i] = mn;
      float rs = 0.f;
#pragma unroll
      for (int kc = 0; kc < 4; ++kc) {
        float p = __expf(s4[kc][i] - mn);
        s4[kc][i] = p;
        rs += p;
      }
#pragma unroll
      for (int dd = 1; dd < 16; dd <<= 1)
        rs += __shfl_xor(rs, dd, 64);
      lI[i] = lI[i] * alpha[i] + rs;
    }

    // ---- P -> per-wave LDS (bf16), C-layout -> A-layout transpose ----
    unsigned short* pw = &Ps[w][0];
#pragma unroll
    for (int kc = 0; kc < 4; ++kc)
#pragma unroll
      for (int i = 0; i < 4; ++i)
        pw[(g * 4 + i) * 72 + kc * 16 + lr] = f2b(s4[kc][i]);

    // rescale O accumulator
#pragma unroll
    for (int n = 0; n < 4; ++n)
#pragma unroll
      for (int i = 0; i < 4; ++i)
        o[n][i] *= alpha[i];

    // cross-lane LDS dependency within the wave: drain DS queue
    asm volatile("s_waitcnt lgkmcnt(0)" ::: "memory");

    // ---- O += P V ----
#pragma unroll
    for (int kk = 0; kk < 2; ++kk) {
      s16x8 pf = *(const s16x8*)&Ps[w][lr * 72 + kk * 32 + g * 8];
#pragma unroll
      for (int n = 0; n < 4; ++n) {
        int d = n * 16 + lr;
        int sw = ((d ^ (d >> 3)) & 7) << 4;
        s16x8 vf = *(const s16x8*)((const char*)Vt + d * 144 + ((kk * 64 + g * 16) ^ sw));
        o[n] = mfma16(pf, vf, o[n]);
      }
    }
  }

  // ---- epilogue: divide by l, write bf16 ----
  float rl[4];
#pragma unroll
  for (int i = 0; i < 4; ++i) rl[i] = 1.f / lI[i];
#pragma unroll
  for (int n = 0; n < 4; ++n)
#pragma unroll
    for (int i = 0; i < 4; ++i) {
      int row = qr + g * 4 + i;
      int col = h * 64 + n * 16 + lr;
      out[(rb + row) * 1024 + col] = f2b(o[n][i] * rl[i]);
    }
}

// ---------------- launcher ----------------
extern "C" void kernel_launch(void* const* d_in, const int* in_sizes, int n_in,
                              void* d_out, int out_size, void* d_ws, size_t ws_size,
                              hipStream_t stream) {
  const float* x     = (const float*)d_in[0];
  const float* w_qkv = (const float*)d_in[1];
  const float* w_out = (const float*)d_in[2];

  const size_t n_x   = (size_t)BATCH * T_SEQ * DM;     // 8.39M
  const size_t n_wq  = (size_t)3 * DM * DM;            // 3.15M
  const size_t n_wo  = (size_t)DM * DM;                // 1.05M
  const size_t n_qkv = (size_t)BATCH * T_SEQ * 3 * DM; // 25.2M
  const size_t need  = (n_x + n_wq + n_wo + n_qkv + n_x) * 2;
  if (ws_size < need) return;  // workspace too small: leave output poisoned (visible failure)

  unsigned short* xb  = (unsigned short*)d_ws;
  unsigned short* wqb = xb + n_x;
  unsigned short* wob = wqb + n_wq;
  unsigned short* qkv = wob + n_wo;
  unsigned short* att = qkv + n_qkv;

  cvt_f32_bf16<<<2048, 256, 0, stream>>>(x, xb, (int)(n_x / 4));
  cvt_f32_bf16<<<1024, 256, 0, stream>>>(w_qkv, wqb, (int)(n_wq / 4));
  cvt_f32_bf16<<<512, 256, 0, stream>>>(w_out, wob, (int)(n_wo / 4));

  gemm_bt<0><<<dim3(64, 24), 256, 0, stream>>>(xb, wqb, qkv, BATCH * T_SEQ, 3 * DM, DM);
  attn_kernel<<<dim3(T_SEQ / 64, BATCH * NH), 256, 0, stream>>>(qkv, att);
  gemm_bt<1><<<dim3(64, 8), 256, 0, stream>>>(att, wob, d_out, BATCH * T_SEQ, DM, DM);
}

// Round 3
// 302.092 us; speedup vs baseline: 1.2447x; 1.2447x over previous
//
#include <hip/hip_runtime.h>
#include <hip/hip_bf16.h>

#define T_SEQ 2048
#define BATCH 4
#define NH    16
#define DM    1024
#define HD    64

typedef __attribute__((ext_vector_type(4))) float  f32x4;
typedef __attribute__((ext_vector_type(8))) short  s16x8;
typedef __attribute__((ext_vector_type(4))) short  s16x4;

__device__ __forceinline__ unsigned short f2b(float f) {
  union { float f; unsigned u; } v; v.f = f;
  unsigned u = v.u;
  unsigned r = 0x7fffu + ((u >> 16) & 1u);
  u += r;
  return (unsigned short)(u >> 16);
}

__device__ __forceinline__ f32x4 mfma16(s16x8 a, s16x8 b, f32x4 c) {
  return __builtin_amdgcn_mfma_f32_16x16x32_bf16(a, b, c, 0, 0, 0);
}

// ---------------- fp32 -> bf16 convert (vectorized) ----------------
__global__ void cvt_f32_bf16(const float* __restrict__ src,
                             unsigned short* __restrict__ dst, int n4) {
  int i = blockIdx.x * blockDim.x + threadIdx.x;
  int stride = gridDim.x * blockDim.x;
  for (int j = i; j < n4; j += stride) {
    f32x4 v = ((const f32x4*)src)[j];
    s16x4 o;
    o.x = (short)f2b(v.x); o.y = (short)f2b(v.y);
    o.z = (short)f2b(v.z); o.w = (short)f2b(v.w);
    ((s16x4*)dst)[j] = o;
  }
}

// ---------------- GEMM: C[M,N] = A[M,K] * B[N,K]^T  (bf16 in, bf16/f32 out) ----------------
template<int OUT_F32>
__global__ __launch_bounds__(256)
void gemm_bt(const unsigned short* __restrict__ A,
             const unsigned short* __restrict__ B,
             void* __restrict__ C, int M, int N, int K) {
  __shared__ unsigned short As[128 * 40];
  __shared__ unsigned short Bs[128 * 40];
  const int tid  = threadIdx.x;
  const int lane = tid & 63;
  const int w    = tid >> 6;
  const int wr   = w >> 1, wc = w & 1;
  const int lr   = lane & 15, g = lane >> 4;
  const int row0 = blockIdx.x * 128;
  const int col0 = blockIdx.y * 128;

  f32x4 acc[4][4] = {};

  for (int kt = 0; kt < K; kt += 32) {
    __syncthreads();
#pragma unroll
    for (int s = 0; s < 2; ++s) {
      int c = tid + s * 256;
      int r = c >> 2, k0 = (c & 3) * 8;
      *(s16x8*)&As[r * 40 + k0] =
        *(const s16x8*)&A[(size_t)(row0 + r) * K + kt + k0];
      *(s16x8*)&Bs[r * 40 + k0] =
        *(const s16x8*)&B[(size_t)(col0 + r) * K + kt + k0];
    }
    __syncthreads();
    s16x8 af[4], bf[4];
#pragma unroll
    for (int m = 0; m < 4; ++m)
      af[m] = *(const s16x8*)&As[(wr * 64 + m * 16 + lr) * 40 + g * 8];
#pragma unroll
    for (int n = 0; n < 4; ++n)
      bf[n] = *(const s16x8*)&Bs[(wc * 64 + n * 16 + lr) * 40 + g * 8];
#pragma unroll
    for (int m = 0; m < 4; ++m)
#pragma unroll
      for (int n = 0; n < 4; ++n)
        acc[m][n] = mfma16(af[m], bf[n], acc[m][n]);
  }

#pragma unroll
  for (int m = 0; m < 4; ++m)
#pragma unroll
    for (int n = 0; n < 4; ++n)
#pragma unroll
      for (int i = 0; i < 4; ++i) {
        int row = row0 + wr * 64 + m * 16 + g * 4 + i;
        int col = col0 + wc * 64 + n * 16 + lr;
        if (OUT_F32)
          ((float*)C)[(size_t)row * N + col] = acc[m][n][i];
        else
          ((unsigned short*)C)[(size_t)row * N + col] = f2b(acc[m][n][i]);
      }
}

// ---------------- causal flash attention, QBLK=128, 8 waves, dbuf prefetch ----------------
// qkv layout: [B*T, 3072], feature col = f*1024 + h*64 + d
__global__ __launch_bounds__(512, 6)
void attn_kernel(const unsigned short* __restrict__ qkv,
                 unsigned short* __restrict__ out) {
  __shared__ unsigned short Ks[2][64 * 64];   // [buf][row*64 elems], 128B rows, XOR swizzle (row&7)<<4
  __shared__ unsigned short Vt[2][64 * 72];   // [buf][d][144B], key-pairs as u32, byte swizzle
  __shared__ unsigned short Ps[8][16 * 72];   // per-wave P

  const int tid  = threadIdx.x;
  const int lane = tid & 63;
  const int w    = tid >> 6;           // 0..7
  const int lr   = lane & 15, g = lane >> 4;
  const int bh   = blockIdx.x;         // 0..63
  const int qt   = 15 - (int)blockIdx.y;  // heavy tiles dispatch first
  const int b    = bh >> 4, h = bh & 15;
  const int q0   = qt * 128;
  const int qr   = q0 + w * 16;
  const size_t rb = (size_t)b * T_SEQ;

  // Q fragments (A-operand) straight from global
  s16x8 qf[2];
  {
    const unsigned short* qp = qkv + (rb + qr + lr) * 3072 + h * 64;
    qf[0] = *(const s16x8*)(qp + g * 8);
    qf[1] = *(const s16x8*)(qp + 32 + g * 8);
  }

  float mI[4], lI[4];
  f32x4 o[4] = {};
#pragma unroll
  for (int i = 0; i < 4; ++i) { mI[i] = -1e30f; lI[i] = 0.f; }

  const int nt   = 2 * qt + 2;
  const int qmax = qr + 15;

  // staging roles: waves 0-3 stage V (row pairs), waves 4-7 stage K (2 chunks)
  const bool grpV = (tid < 256);
  const int vd0 = (tid & 7) * 8, vr0 = (tid >> 3) * 2;
  const int t2  = tid - 256;
  const int kr0 = t2 >> 3, kc0 = t2 & 7;        // chunk 1 = row kr0+32, same col

  s16x8 pre0, pre1;
  {  // issue tile 0
    if (grpV) {
      const unsigned short* vp = &qkv[(rb + vr0) * 3072 + 2048 + h * 64 + vd0];
      pre0 = *(const s16x8*)vp;
      pre1 = *(const s16x8*)(vp + 3072);
    } else {
      const unsigned short* kp = &qkv[(rb + kr0) * 3072 + 1024 + h * 64 + kc0 * 8];
      pre0 = *(const s16x8*)kp;
      pre1 = *(const s16x8*)(kp + 32 * 3072);
    }
  }

  for (int t = 0; t < nt; ++t) {
    const int cur = t & 1;
    // ---- commit tile t regs -> LDS[cur] ----
    if (grpV) {
#pragma unroll
      for (int jj = 0; jj < 8; ++jj) {
        int d = vd0 + jj;
        int sw = ((d ^ (d >> 3)) & 7) << 4;
        unsigned val = (unsigned)(unsigned short)pre0[jj] |
                       ((unsigned)(unsigned short)pre1[jj] << 16);
        *(unsigned*)((char*)&Vt[cur][0] + d * 144 + ((vr0 * 2) ^ sw)) = val;
      }
    } else {
      *(s16x8*)((char*)&Ks[cur][0] + kr0 * 128 + ((kc0 * 16) ^ ((kr0 & 7) << 4))) = pre0;
      int kr1 = kr0 + 32;
      *(s16x8*)((char*)&Ks[cur][0] + kr1 * 128 + ((kc0 * 16) ^ ((kr1 & 7) << 4))) = pre1;
    }
    // ---- issue tile t+1 loads (overlap with barrier+compute) ----
    if (t + 1 < nt) {
      const int kv0n = (t + 1) * 64;
      if (grpV) {
        const unsigned short* vp = &qkv[(rb + kv0n + vr0) * 3072 + 2048 + h * 64 + vd0];
        pre0 = *(const s16x8*)vp;
        pre1 = *(const s16x8*)(vp + 3072);
      } else {
        const unsigned short* kp = &qkv[(rb + kv0n + kr0) * 3072 + 1024 + h * 64 + kc0 * 8];
        pre0 = *(const s16x8*)kp;
        pre1 = *(const s16x8*)(kp + 32 * 3072);
      }
    }
    __syncthreads();

    const int kv0 = t * 64;
    if (kv0 <= qmax) {   // wave-uniform: skip fully-masked tiles
      // ---- S = Q K^T ----
      f32x4 s4[4];
#pragma unroll
      for (int kc = 0; kc < 4; ++kc) {
        int row = kc * 16 + lr;
        const char* kbase = (const char*)&Ks[cur][0] + row * 128;
        int sw = (row & 7) << 4;
        s16x8 kf0 = *(const s16x8*)(kbase + ((g * 16) ^ sw));
        s16x8 kf1 = *(const s16x8*)(kbase + ((64 + g * 16) ^ sw));
        f32x4 s = {};
        s = mfma16(qf[0], kf0, s);
        s = mfma16(qf[1], kf1, s);
        s4[kc] = s;
      }

      // ---- scale + causal mask ----
#pragma unroll
      for (int kc = 0; kc < 4; ++kc) {
        int key = kv0 + kc * 16 + lr;
#pragma unroll
        for (int i = 0; i < 4; ++i) {
          int qrow = qr + g * 4 + i;
          float v = s4[kc][i] * 0.125f;
          s4[kc][i] = (key <= qrow) ? v : -1e30f;
        }
      }

      // ---- online softmax (16-lane group reduce) ----
      float alpha[4];
#pragma unroll
      for (int i = 0; i < 4; ++i) {
        float mx = fmaxf(fmaxf(s4[0][i], s4[1][i]), fmaxf(s4[2][i], s4[3][i]));
#pragma unroll
        for (int dd = 1; dd < 16; dd <<= 1)
          mx = fmaxf(mx, __shfl_xor(mx, dd, 64));
        float mn = fmaxf(mI[i], mx);
        alpha[i] = __expf(mI[i] - mn);
        mI[i] = mn;
        float rs = 0.f;
#pragma unroll
        for (int kc = 0; kc < 4; ++kc) {
          float p = __expf(s4[kc][i] - mn);
          s4[kc][i] = p;
          rs += p;
        }
#pragma unroll
        for (int dd = 1; dd < 16; dd <<= 1)
          rs += __shfl_xor(rs, dd, 64);
        lI[i] = lI[i] * alpha[i] + rs;
      }

      // ---- P -> per-wave LDS (C-layout -> A-layout) ----
      unsigned short* pw = &Ps[w][0];
#pragma unroll
      for (int kc = 0; kc < 4; ++kc)
#pragma unroll
        for (int i = 0; i < 4; ++i)
          pw[(g * 4 + i) * 72 + kc * 16 + lr] = f2b(s4[kc][i]);

      // rescale O
#pragma unroll
      for (int n = 0; n < 4; ++n)
#pragma unroll
        for (int i = 0; i < 4; ++i)
          o[n][i] *= alpha[i];

      asm volatile("s_waitcnt lgkmcnt(0)" ::: "memory");

      // ---- O += P V ----
#pragma unroll
      for (int kk = 0; kk < 2; ++kk) {
        s16x8 pf = *(const s16x8*)&Ps[w][lr * 72 + kk * 32 + g * 8];
#pragma unroll
        for (int n = 0; n < 4; ++n) {
          int d = n * 16 + lr;
          int sw = ((d ^ (d >> 3)) & 7) << 4;
          s16x8 vf = *(const s16x8*)((const char*)&Vt[cur][0] + d * 144 + ((kk * 64 + g * 16) ^ sw));
          o[n] = mfma16(pf, vf, o[n]);
        }
      }
    }
  }

  // ---- epilogue ----
  float rl[4];
#pragma unroll
  for (int i = 0; i < 4; ++i) rl[i] = 1.f / lI[i];
#pragma unroll
  for (int n = 0; n < 4; ++n)
#pragma unroll
    for (int i = 0; i < 4; ++i) {
      int row = qr + g * 4 + i;
      int col = h * 64 + n * 16 + lr;
      out[(rb + row) * 1024 + col] = f2b(o[n][i] * rl[i]);
    }
}

// ---------------- launcher ----------------
extern "C" void kernel_launch(void* const* d_in, const int* in_sizes, int n_in,
                              void* d_out, int out_size, void* d_ws, size_t ws_size,
                              hipStream_t stream) {
  const float* x     = (const float*)d_in[0];
  const float* w_qkv = (const float*)d_in[1];
  const float* w_out = (const float*)d_in[2];

  const size_t n_x   = (size_t)BATCH * T_SEQ * DM;
  const size_t n_wq  = (size_t)3 * DM * DM;
  const size_t n_wo  = (size_t)DM * DM;
  const size_t n_qkv = (size_t)BATCH * T_SEQ * 3 * DM;
  const size_t need  = (n_x + n_wq + n_wo + n_qkv + n_x) * 2;
  if (ws_size < need) return;

  unsigned short* xb  = (unsigned short*)d_ws;
  unsigned short* wqb = xb + n_x;
  unsigned short* wob = wqb + n_wq;
  unsigned short* qkv = wob + n_wo;
  unsigned short* att = qkv + n_qkv;

  cvt_f32_bf16<<<2048, 256, 0, stream>>>(x, xb, (int)(n_x / 4));
  cvt_f32_bf16<<<1024, 256, 0, stream>>>(w_qkv, wqb, (int)(n_wq / 4));
  cvt_f32_bf16<<<512, 256, 0, stream>>>(w_out, wob, (int)(n_wo / 4));

  gemm_bt<0><<<dim3(64, 24), 256, 0, stream>>>(xb, wqb, qkv, BATCH * T_SEQ, 3 * DM, DM);
  attn_kernel<<<dim3(BATCH * NH, T_SEQ / 128), 512, 0, stream>>>(qkv, att);
  gemm_bt<1><<<dim3(64, 8), 256, 0, stream>>>(att, wob, d_out, BATCH * T_SEQ, DM, DM);
}

// Round 4
// 212.273 us; speedup vs baseline: 1.7714x; 1.4231x over previous
//
#include <hip/hip_runtime.h>
#include <hip/hip_bf16.h>

#define T_SEQ 2048
#define BATCH 4
#define NH    16
#define DM    1024
#define HD    64

typedef __attribute__((ext_vector_type(4))) float  f32x4;
typedef __attribute__((ext_vector_type(8))) short  s16x8;
typedef __attribute__((ext_vector_type(4))) short  s16x4;
typedef __attribute__((ext_vector_type(4))) unsigned short u16x4;

__device__ __forceinline__ unsigned short f2b(float f) {
  union { float f; unsigned u; } v; v.f = f;
  unsigned u = v.u;
  unsigned r = 0x7fffu + ((u >> 16) & 1u);
  u += r;
  return (unsigned short)(u >> 16);
}

__device__ __forceinline__ f32x4 mfma16(s16x8 a, s16x8 b, f32x4 c) {
  return __builtin_amdgcn_mfma_f32_16x16x32_bf16(a, b, c, 0, 0, 0);
}

// ---------------- fp32 -> bf16 convert (vectorized) ----------------
__global__ void cvt_f32_bf16(const float* __restrict__ src,
                             unsigned short* __restrict__ dst, int n4) {
  int i = blockIdx.x * blockDim.x + threadIdx.x;
  int stride = gridDim.x * blockDim.x;
  for (int j = i; j < n4; j += stride) {
    f32x4 v = ((const f32x4*)src)[j];
    s16x4 o;
    o.x = (short)f2b(v.x); o.y = (short)f2b(v.y);
    o.z = (short)f2b(v.z); o.w = (short)f2b(v.w);
    ((s16x4*)dst)[j] = o;
  }
}

// ---------------- GEMM: C[M,N] = A[M,K] * B[N,K]^T, global_load_lds staging ----------------
template<int OUT_F32>
__global__ __launch_bounds__(256)
void gemm_bt(const unsigned short* __restrict__ A,
             const unsigned short* __restrict__ B,
             void* __restrict__ C, int M, int N, int K) {
  __shared__ unsigned short As[128 * 32];   // [row][32k], linear (m97 structure)
  __shared__ unsigned short Bs[128 * 32];
  const int tid  = threadIdx.x;
  const int lane = tid & 63;
  const int w    = tid >> 6;
  const int wr   = w >> 1, wc = w & 1;
  const int lr   = lane & 15, g = lane >> 4;

  // XCD-aware bijective swizzle (grid % 8 == 0 for both GEMMs)
  const int gx  = gridDim.x, nwg = gx * gridDim.y;
  const int bid = blockIdx.y * gx + blockIdx.x;
  const int qq  = nwg >> 3;
  const int b2  = (bid & 7) * qq + (bid >> 3);
  const int row0 = (b2 % gx) * 128;
  const int col0 = (b2 / gx) * 128;

  const int srow = w * 16 + (lane >> 2);      // staging row within 64-row stripe
  const int scol = (lane & 3) * 8;            // staging k-offset (elems)

  f32x4 acc[4][4] = {};

  for (int kt = 0; kt < K; kt += 32) {
    __syncthreads();
#pragma unroll
    for (int s = 0; s < 2; ++s) {
      const unsigned short* srcA = A + (size_t)(row0 + s * 64 + srow) * K + kt + scol;
      __builtin_amdgcn_global_load_lds((const void*)srcA, (void*)&As[(s * 64 + w * 16) * 32], 16, 0, 0);
      const unsigned short* srcB = B + (size_t)(col0 + s * 64 + srow) * K + kt + scol;
      __builtin_amdgcn_global_load_lds((const void*)srcB, (void*)&Bs[(s * 64 + w * 16) * 32], 16, 0, 0);
    }
    __syncthreads();   // compiler drains vmcnt(0) before s_barrier

    s16x8 af[4], bf[4];
#pragma unroll
    for (int m = 0; m < 4; ++m)
      af[m] = *(const s16x8*)&As[(wr * 64 + m * 16 + lr) * 32 + g * 8];
#pragma unroll
    for (int n = 0; n < 4; ++n)
      bf[n] = *(const s16x8*)&Bs[(wc * 64 + n * 16 + lr) * 32 + g * 8];
#pragma unroll
    for (int m = 0; m < 4; ++m)
#pragma unroll
      for (int n = 0; n < 4; ++n)
        acc[m][n] = mfma16(af[m], bf[n], acc[m][n]);
  }

#pragma unroll
  for (int m = 0; m < 4; ++m)
#pragma unroll
    for (int n = 0; n < 4; ++n)
#pragma unroll
      for (int i = 0; i < 4; ++i) {
        int row = row0 + wr * 64 + m * 16 + g * 4 + i;
        int col = col0 + wc * 64 + n * 16 + lr;
        if (OUT_F32)
          ((float*)C)[(size_t)row * N + col] = acc[m][n][i];
        else
          ((unsigned short*)C)[(size_t)row * N + col] = f2b(acc[m][n][i]);
      }
}

// ---------------- causal flash attention, swapped QK^T (in-register softmax) ----------------
// qkv layout: [B*T, 3072], feature col = f*1024 + h*64 + d
__global__ __launch_bounds__(512)
void attn_kernel(const unsigned short* __restrict__ qkv,
                 unsigned short* __restrict__ out) {
  __shared__ unsigned short Ks[2][64 * 64];   // [buf][key][64d], 128B rows, XOR swizzle (row&7)<<4
  __shared__ unsigned short Vt[2][64 * 72];   // [buf][d][144B], key-pairs as u32, byte swizzle
  __shared__ unsigned short Ps[8][16 * 72];   // per-wave P, [q][key], stride 72

  const int tid  = threadIdx.x;
  const int lane = tid & 63;
  const int w    = tid >> 6;           // 0..7
  const int lr   = lane & 15, g = lane >> 4;
  const int bh   = blockIdx.x;         // 0..63
  const int qt   = 15 - (int)blockIdx.y;  // heavy tiles dispatch first
  const int b    = bh >> 4, h = bh & 15;
  const int q0   = qt * 128;
  const int qr   = q0 + w * 16;        // wave's first q row
  const int qq   = qr + lr;            // THIS lane's query row
  const size_t rb = (size_t)b * T_SEQ;

  // Q fragment, B-operand: B[k=d][col=q]: lane col=lr -> q=qr+lr, d=g*8+j
  s16x8 qf[2];
  {
    const unsigned short* qp = qkv + (rb + qq) * 3072 + h * 64;
    qf[0] = *(const s16x8*)(qp + g * 8);
    qf[1] = *(const s16x8*)(qp + 32 + g * 8);
  }

  float mI = -1e30f, lI = 0.f;
  f32x4 o[4] = {};

  const int nt   = 2 * qt + 2;
  const int qmax = qr + 15;

  // staging roles: threads 0-255 stage V (row pairs), 256-511 stage K
  const bool grpV = (tid < 256);
  const int vd0 = (tid & 7) * 8, vr0 = (tid >> 3) * 2;
  const int t2  = tid - 256;
  const int kr0 = t2 >> 3, kc0 = t2 & 7;

  s16x8 pre0, pre1;
  {  // issue tile 0
    if (grpV) {
      const unsigned short* vp = &qkv[(rb + vr0) * 3072 + 2048 + h * 64 + vd0];
      pre0 = *(const s16x8*)vp;
      pre1 = *(const s16x8*)(vp + 3072);
    } else {
      const unsigned short* kp = &qkv[(rb + kr0) * 3072 + 1024 + h * 64 + kc0 * 8];
      pre0 = *(const s16x8*)kp;
      pre1 = *(const s16x8*)(kp + 32 * 3072);
    }
  }

  for (int t = 0; t < nt; ++t) {
    const int cur = t & 1;
    // ---- commit tile t regs -> LDS[cur] ----
    if (grpV) {
#pragma unroll
      for (int jj = 0; jj < 8; ++jj) {
        int d = vd0 + jj;
        int sw = ((d ^ (d >> 3)) & 7) << 4;
        unsigned val = (unsigned)(unsigned short)pre0[jj] |
                       ((unsigned)(unsigned short)pre1[jj] << 16);
        *(unsigned*)((char*)&Vt[cur][0] + d * 144 + ((vr0 * 2) ^ sw)) = val;
      }
    } else {
      *(s16x8*)((char*)&Ks[cur][0] + kr0 * 128 + ((kc0 * 16) ^ ((kr0 & 7) << 4))) = pre0;
      int kr1 = kr0 + 32;
      *(s16x8*)((char*)&Ks[cur][0] + kr1 * 128 + ((kc0 * 16) ^ ((kr1 & 7) << 4))) = pre1;
    }
    // ---- issue tile t+1 loads ----
    if (t + 1 < nt) {
      const int kv0n = (t + 1) * 64;
      if (grpV) {
        const unsigned short* vp = &qkv[(rb + kv0n + vr0) * 3072 + 2048 + h * 64 + vd0];
        pre0 = *(const s16x8*)vp;
        pre1 = *(const s16x8*)(vp + 3072);
      } else {
        const unsigned short* kp = &qkv[(rb + kv0n + kr0) * 3072 + 1024 + h * 64 + kc0 * 8];
        pre0 = *(const s16x8*)kp;
        pre1 = *(const s16x8*)(kp + 32 * 3072);
      }
    }
    __syncthreads();

    const int kv0 = t * 64;
    if (kv0 <= qmax) {
      // ---- S^T = K Q^T : C[row=key][col=q], lane holds 16 keys for query qq ----
      f32x4 s4[4];
      __builtin_amdgcn_s_setprio(1);
#pragma unroll
      for (int kc = 0; kc < 4; ++kc) {
        int row = kc * 16 + lr;
        const char* kbase = (const char*)&Ks[cur][0] + row * 128;
        int sw = (row & 7) << 4;
        s16x8 kf0 = *(const s16x8*)(kbase + ((g * 16) ^ sw));
        s16x8 kf1 = *(const s16x8*)(kbase + ((64 + g * 16) ^ sw));
        f32x4 s = {};
        s = mfma16(kf0, qf[0], s);
        s = mfma16(kf1, qf[1], s);
        s4[kc] = s;
      }
      __builtin_amdgcn_s_setprio(0);

      // ---- scale + causal mask (all 16 values belong to query qq) ----
#pragma unroll
      for (int kc = 0; kc < 4; ++kc)
#pragma unroll
        for (int i = 0; i < 4; ++i) {
          int key = kv0 + kc * 16 + g * 4 + i;
          float v = s4[kc][i] * 0.125f;
          s4[kc][i] = (key <= qq) ? v : -1e30f;
        }

      // ---- online softmax: in-register reduce + 2 cross-g shuffles ----
      float mx0 = fmaxf(fmaxf(s4[0][0], s4[0][1]), fmaxf(s4[0][2], s4[0][3]));
      float mx1 = fmaxf(fmaxf(s4[1][0], s4[1][1]), fmaxf(s4[1][2], s4[1][3]));
      float mx2 = fmaxf(fmaxf(s4[2][0], s4[2][1]), fmaxf(s4[2][2], s4[2][3]));
      float mx3 = fmaxf(fmaxf(s4[3][0], s4[3][1]), fmaxf(s4[3][2], s4[3][3]));
      float mx = fmaxf(fmaxf(mx0, mx1), fmaxf(mx2, mx3));
      mx = fmaxf(mx, __shfl_xor(mx, 16));
      mx = fmaxf(mx, __shfl_xor(mx, 32));
      float mn = fmaxf(mI, mx);
      float alpha = __expf(mI - mn);
      mI = mn;
      float rs = 0.f;
#pragma unroll
      for (int kc = 0; kc < 4; ++kc)
#pragma unroll
        for (int i = 0; i < 4; ++i) {
          float p = __expf(s4[kc][i] - mn);
          s4[kc][i] = p;
          rs += p;
        }
      rs += __shfl_xor(rs, 16);
      rs += __shfl_xor(rs, 32);
      lI = lI * alpha + rs;

      // ---- P -> per-wave LDS, row-major [q][key] (u32-packed) ----
      {
        char* pw = (char*)&Ps[w][0] + lr * 144;
#pragma unroll
        for (int kc = 0; kc < 4; ++kc) {
          unsigned v0 = (unsigned)f2b(s4[kc][0]) | ((unsigned)f2b(s4[kc][1]) << 16);
          unsigned v1 = (unsigned)f2b(s4[kc][2]) | ((unsigned)f2b(s4[kc][3]) << 16);
          *(unsigned*)(pw + kc * 32 + g * 8)     = v0;
          *(unsigned*)(pw + kc * 32 + g * 8 + 4) = v1;
        }
      }

      // rescale O (single alpha per lane)
#pragma unroll
      for (int n = 0; n < 4; ++n)
#pragma unroll
        for (int i = 0; i < 4; ++i)
          o[n][i] *= alpha;

      asm volatile("s_waitcnt lgkmcnt(0)" ::: "memory");

      // ---- O^T += V^T P : A = V^T frag, B = P frag ----
      __builtin_amdgcn_s_setprio(1);
#pragma unroll
      for (int kk = 0; kk < 2; ++kk) {
        s16x8 pf = *(const s16x8*)((const char*)&Ps[w][0] + lr * 144 + kk * 64 + g * 16);
#pragma unroll
        for (int n = 0; n < 4; ++n) {
          int d = n * 16 + lr;
          int sw = ((d ^ (d >> 3)) & 7) << 4;
          s16x8 vf = *(const s16x8*)((const char*)&Vt[cur][0] + d * 144 + ((kk * 64 + g * 16) ^ sw));
          o[n] = mfma16(vf, pf, o[n]);
        }
      }
      __builtin_amdgcn_s_setprio(0);
    }
  }

  // ---- epilogue: lane holds O[qq][n*16 + g*4 + i] ----
  float rl = 1.f / lI;
#pragma unroll
  for (int n = 0; n < 4; ++n) {
    u16x4 pk;
#pragma unroll
    for (int i = 0; i < 4; ++i) pk[i] = f2b(o[n][i] * rl);
    *(u16x4*)&out[(rb + qq) * 1024 + h * 64 + n * 16 + g * 4] = pk;
  }
}

// ---------------- launcher ----------------
extern "C" void kernel_launch(void* const* d_in, const int* in_sizes, int n_in,
                              void* d_out, int out_size, void* d_ws, size_t ws_size,
                              hipStream_t stream) {
  const float* x     = (const float*)d_in[0];
  const float* w_qkv = (const float*)d_in[1];
  const float* w_out = (const float*)d_in[2];

  const size_t n_x   = (size_t)BATCH * T_SEQ * DM;
  const size_t n_wq  = (size_t)3 * DM * DM;
  const size_t n_wo  = (size_t)DM * DM;
  const size_t n_qkv = (size_t)BATCH * T_SEQ * 3 * DM;
  const size_t need  = (n_x + n_wq + n_wo + n_qkv + n_x) * 2;
  if (ws_size < need) return;

  unsigned short* xb  = (unsigned short*)d_ws;
  unsigned short* wqb = xb + n_x;
  unsigned short* wob = wqb + n_wq;
  unsigned short* qkv = wob + n_wo;
  unsigned short* att = qkv + n_qkv;

  cvt_f32_bf16<<<2048, 256, 0, stream>>>(x, xb, (int)(n_x / 4));
  cvt_f32_bf16<<<1024, 256, 0, stream>>>(w_qkv, wqb, (int)(n_wq / 4));
  cvt_f32_bf16<<<512, 256, 0, stream>>>(w_out, wob, (int)(n_wo / 4));

  gemm_bt<0><<<dim3(64, 24), 256, 0, stream>>>(xb, wqb, qkv, BATCH * T_SEQ, 3 * DM, DM);
  attn_kernel<<<dim3(BATCH * NH, T_SEQ / 128), 512, 0, stream>>>(qkv, att);
  gemm_bt<1><<<dim3(64, 8), 256, 0, stream>>>(att, wob, d_out, BATCH * T_SEQ, DM, DM);
}

// Round 5
// 204.559 us; speedup vs baseline: 1.8382x; 1.0377x over previous
//
#include <hip/hip_runtime.h>
#include <hip/hip_bf16.h>

#define T_SEQ 2048
#define BATCH 4
#define NH    16
#define DM    1024
#define HD    64

typedef __attribute__((ext_vector_type(4))) float  f32x4;
typedef __attribute__((ext_vector_type(8))) short  s16x8;
typedef __attribute__((ext_vector_type(4))) short  s16x4;
typedef __attribute__((ext_vector_type(4))) unsigned short u16x4;

__device__ __forceinline__ unsigned short f2b(float f) {
  union { float f; unsigned u; } v; v.f = f;
  unsigned u = v.u;
  unsigned r = 0x7fffu + ((u >> 16) & 1u);
  u += r;
  return (unsigned short)(u >> 16);
}

__device__ __forceinline__ f32x4 mfma16(s16x8 a, s16x8 b, f32x4 c) {
  return __builtin_amdgcn_mfma_f32_16x16x32_bf16(a, b, c, 0, 0, 0);
}

// ---------------- fused fp32 -> bf16 convert; Q-rows of w_qkv pre-scaled by 1/8 ----------------
__global__ void cvt_all(const float* __restrict__ x, const float* __restrict__ wq,
                        const float* __restrict__ wo,
                        unsigned short* __restrict__ xb, unsigned short* __restrict__ wqb,
                        unsigned short* __restrict__ wob) {
  const int N4X = (BATCH * T_SEQ * DM) / 4;       // 2097152
  const int N4Q = (3 * DM * DM) / 4;              // 786432
  const int N4O = (DM * DM) / 4;                  // 262144
  const int N4QSCALED = (DM * DM) / 4;            // first 1024 rows of w_qkv = Q weights
  int i = blockIdx.x * blockDim.x + threadIdx.x;
  int stride = gridDim.x * blockDim.x;
  for (int j = i; j < N4X + N4Q + N4O; j += stride) {
    const float* src; unsigned short* dst; int k; float scale = 1.f;
    if (j < N4X) { src = x; dst = xb; k = j; }
    else if (j < N4X + N4Q) {
      k = j - N4X; src = wq; dst = wqb;
      if (k < N4QSCALED) scale = 0.125f;          // exact: pow2 scale commutes with bf16 round
    } else { k = j - N4X - N4Q; src = wo; dst = wob; }
    f32x4 v = ((const f32x4*)src)[k];
    s16x4 o;
    o.x = (short)f2b(v.x * scale); o.y = (short)f2b(v.y * scale);
    o.z = (short)f2b(v.z * scale); o.w = (short)f2b(v.w * scale);
    ((s16x4*)dst)[k] = o;
  }
}

// ---------------- GEMM: C[M,N] = A[M,K] * B[N,K]^T, global_load_lds staging ----------------
template<int OUT_F32>
__global__ __launch_bounds__(256)
void gemm_bt(const unsigned short* __restrict__ A,
             const unsigned short* __restrict__ B,
             void* __restrict__ C, int M, int N, int K) {
  __shared__ unsigned short As[128 * 32];
  __shared__ unsigned short Bs[128 * 32];
  const int tid  = threadIdx.x;
  const int lane = tid & 63;
  const int w    = tid >> 6;
  const int wr   = w >> 1, wc = w & 1;
  const int lr   = lane & 15, g = lane >> 4;

  const int gx  = gridDim.x, nwg = gx * gridDim.y;
  const int bid = blockIdx.y * gx + blockIdx.x;
  const int qq  = nwg >> 3;
  const int b2  = (bid & 7) * qq + (bid >> 3);
  const int row0 = (b2 % gx) * 128;
  const int col0 = (b2 / gx) * 128;

  const int srow = w * 16 + (lane >> 2);
  const int scol = (lane & 3) * 8;

  f32x4 acc[4][4] = {};

  for (int kt = 0; kt < K; kt += 32) {
    __syncthreads();
#pragma unroll
    for (int s = 0; s < 2; ++s) {
      const unsigned short* srcA = A + (size_t)(row0 + s * 64 + srow) * K + kt + scol;
      __builtin_amdgcn_global_load_lds((const void*)srcA, (void*)&As[(s * 64 + w * 16) * 32], 16, 0, 0);
      const unsigned short* srcB = B + (size_t)(col0 + s * 64 + srow) * K + kt + scol;
      __builtin_amdgcn_global_load_lds((const void*)srcB, (void*)&Bs[(s * 64 + w * 16) * 32], 16, 0, 0);
    }
    __syncthreads();

    s16x8 af[4], bf[4];
#pragma unroll
    for (int m = 0; m < 4; ++m)
      af[m] = *(const s16x8*)&As[(wr * 64 + m * 16 + lr) * 32 + g * 8];
#pragma unroll
    for (int n = 0; n < 4; ++n)
      bf[n] = *(const s16x8*)&Bs[(wc * 64 + n * 16 + lr) * 32 + g * 8];
#pragma unroll
    for (int m = 0; m < 4; ++m)
#pragma unroll
      for (int n = 0; n < 4; ++n)
        acc[m][n] = mfma16(af[m], bf[n], acc[m][n]);
  }

#pragma unroll
  for (int m = 0; m < 4; ++m)
#pragma unroll
    for (int n = 0; n < 4; ++n)
#pragma unroll
      for (int i = 0; i < 4; ++i) {
        int row = row0 + wr * 64 + m * 16 + g * 4 + i;
        int col = col0 + wc * 64 + n * 16 + lr;
        if (OUT_F32)
          ((float*)C)[(size_t)row * N + col] = acc[m][n][i];
        else
          ((unsigned short*)C)[(size_t)row * N + col] = f2b(acc[m][n][i]);
      }
}

// ---------------- causal flash attention, swapped QK^T, VALU diet ----------------
// qkv layout: [B*T, 3072]; Q pre-scaled by 1/8 via weights
__global__ __launch_bounds__(512)
void attn_kernel(const unsigned short* __restrict__ qkv,
                 unsigned short* __restrict__ out) {
  __shared__ unsigned short Ks[2][64 * 64];   // [buf][key][64d], 128B rows, XOR swizzle (row&7)<<4
  __shared__ unsigned short Vt[2][64 * 72];   // [buf][d][144B], key-pairs as u32, byte swizzle
  __shared__ unsigned short Ps[8][16 * 72];   // per-wave P, [q][key], stride 72

  const int tid  = threadIdx.x;
  const int lane = tid & 63;
  const int w    = tid >> 6;
  const int lr   = lane & 15, g = lane >> 4;
  const int bh   = blockIdx.x;
  const int qt   = 15 - (int)blockIdx.y;
  const int b    = bh >> 4, h = bh & 15;
  const int q0   = qt * 128;
  const int qr   = q0 + w * 16;
  const int qq   = qr + lr;            // this lane's query row
  const size_t rb = (size_t)b * T_SEQ;

  s16x8 qf[2];
  {
    const unsigned short* qp = qkv + (rb + qq) * 3072 + h * 64;
    qf[0] = *(const s16x8*)(qp + g * 8);
    qf[1] = *(const s16x8*)(qp + 32 + g * 8);
  }

  float mI = -1e30f, lI = 0.f;
  f32x4 o[4] = {};

  const int nt   = 2 * qt + 2;
  const int qmax = qr + 15;

  const bool grpV = (tid < 256);
  const int vd0 = (tid & 7) * 8, vr0 = (tid >> 3) * 2;
  const int t2  = tid - 256;
  const int kr0 = t2 >> 3, kc0 = t2 & 7;

  s16x8 pre0, pre1;
  {
    if (grpV) {
      const unsigned short* vp = &qkv[(rb + vr0) * 3072 + 2048 + h * 64 + vd0];
      pre0 = *(const s16x8*)vp;
      pre1 = *(const s16x8*)(vp + 3072);
    } else {
      const unsigned short* kp = &qkv[(rb + kr0) * 3072 + 1024 + h * 64 + kc0 * 8];
      pre0 = *(const s16x8*)kp;
      pre1 = *(const s16x8*)(kp + 32 * 3072);
    }
  }

  for (int t = 0; t < nt; ++t) {
    const int cur = t & 1;
    // ---- commit tile t regs -> LDS[cur] ----
    if (grpV) {
#pragma unroll
      for (int jj = 0; jj < 8; ++jj) {
        int d = vd0 + jj;
        int sw = ((d ^ (d >> 3)) & 7) << 4;
        unsigned val = (unsigned)(unsigned short)pre0[jj] |
                       ((unsigned)(unsigned short)pre1[jj] << 16);
        *(unsigned*)((char*)&Vt[cur][0] + d * 144 + ((vr0 * 2) ^ sw)) = val;
      }
    } else {
      *(s16x8*)((char*)&Ks[cur][0] + kr0 * 128 + ((kc0 * 16) ^ ((kr0 & 7) << 4))) = pre0;
      int kr1 = kr0 + 32;
      *(s16x8*)((char*)&Ks[cur][0] + kr1 * 128 + ((kc0 * 16) ^ ((kr1 & 7) << 4))) = pre1;
    }
    // ---- issue tile t+1 loads ----
    if (t + 1 < nt) {
      const int kv0n = (t + 1) * 64;
      if (grpV) {
        const unsigned short* vp = &qkv[(rb + kv0n + vr0) * 3072 + 2048 + h * 64 + vd0];
        pre0 = *(const s16x8*)vp;
        pre1 = *(const s16x8*)(vp + 3072);
      } else {
        const unsigned short* kp = &qkv[(rb + kv0n + kr0) * 3072 + 1024 + h * 64 + kc0 * 8];
        pre0 = *(const s16x8*)kp;
        pre1 = *(const s16x8*)(kp + 32 * 3072);
      }
    }
    __syncthreads();

    const int kv0 = t * 64;
    if (kv0 <= qmax) {
      // ---- S^T = K Q^T (Q pre-scaled) ----
      f32x4 s4[4];
      __builtin_amdgcn_s_setprio(1);
#pragma unroll
      for (int kc = 0; kc < 4; ++kc) {
        int row = kc * 16 + lr;
        const char* kbase = (const char*)&Ks[cur][0] + row * 128;
        int sw = (row & 7) << 4;
        s16x8 kf0 = *(const s16x8*)(kbase + ((g * 16) ^ sw));
        s16x8 kf1 = *(const s16x8*)(kbase + ((64 + g * 16) ^ sw));
        f32x4 s = {};
        s = mfma16(kf0, qf[0], s);
        s = mfma16(kf1, qf[1], s);
        s4[kc] = s;
      }
      __builtin_amdgcn_s_setprio(0);

      // ---- causal mask: only diagonal tiles need it (wave-uniform test) ----
      if (kv0 + 63 > qr) {
#pragma unroll
        for (int kc = 0; kc < 4; ++kc)
#pragma unroll
          for (int i = 0; i < 4; ++i) {
            int key = kv0 + kc * 16 + g * 4 + i;
            if (key > qq) s4[kc][i] = -1e30f;
          }
      }

      // ---- online softmax, in-register + 2 shuffles; defer-max (THR=8) ----
      float mx = fmaxf(fmaxf(fmaxf(s4[0][0], s4[0][1]), fmaxf(s4[0][2], s4[0][3])),
                 fmaxf(fmaxf(fmaxf(s4[1][0], s4[1][1]), fmaxf(s4[1][2], s4[1][3])),
                 fmaxf(fmaxf(fmaxf(s4[2][0], s4[2][1]), fmaxf(s4[2][2], s4[2][3])),
                       fmaxf(fmaxf(s4[3][0], s4[3][1]), fmaxf(s4[3][2], s4[3][3])))));
      mx = fmaxf(mx, __shfl_xor(mx, 16));
      mx = fmaxf(mx, __shfl_xor(mx, 32));

      const bool defer = __all(mx - mI <= 8.f);
      float alpha;
      if (defer) {
        alpha = 1.f;               // keep mI; P bounded by e^8
      } else {
        float mn = fmaxf(mI, mx);
        alpha = __expf(mI - mn);
        mI = mn;
      }
      float rs = 0.f;
#pragma unroll
      for (int kc = 0; kc < 4; ++kc)
#pragma unroll
        for (int i = 0; i < 4; ++i) {
          float p = __expf(s4[kc][i] - mI);
          s4[kc][i] = p;
          rs += p;
        }
      rs += __shfl_xor(rs, 16);
      rs += __shfl_xor(rs, 32);
      lI = lI * alpha + rs;

      // ---- P -> per-wave LDS, row-major [q][key] ----
      {
        char* pw = (char*)&Ps[w][0] + lr * 144;
#pragma unroll
        for (int kc = 0; kc < 4; ++kc) {
          unsigned v0 = (unsigned)f2b(s4[kc][0]) | ((unsigned)f2b(s4[kc][1]) << 16);
          unsigned v1 = (unsigned)f2b(s4[kc][2]) | ((unsigned)f2b(s4[kc][3]) << 16);
          *(unsigned*)(pw + kc * 32 + g * 8)     = v0;
          *(unsigned*)(pw + kc * 32 + g * 8 + 4) = v1;
        }
      }

      if (!defer) {
#pragma unroll
        for (int n = 0; n < 4; ++n)
#pragma unroll
          for (int i = 0; i < 4; ++i)
            o[n][i] *= alpha;
      }

      asm volatile("s_waitcnt lgkmcnt(0)" ::: "memory");

      // ---- O^T += V^T P ----
      __builtin_amdgcn_s_setprio(1);
#pragma unroll
      for (int kk = 0; kk < 2; ++kk) {
        s16x8 pf = *(const s16x8*)((const char*)&Ps[w][0] + lr * 144 + kk * 64 + g * 16);
#pragma unroll
        for (int n = 0; n < 4; ++n) {
          int d = n * 16 + lr;
          int sw = ((d ^ (d >> 3)) & 7) << 4;
          s16x8 vf = *(const s16x8*)((const char*)&Vt[cur][0] + d * 144 + ((kk * 64 + g * 16) ^ sw));
          o[n] = mfma16(vf, pf, o[n]);
        }
      }
      __builtin_amdgcn_s_setprio(0);
    }
  }

  // ---- epilogue ----
  float rl = 1.f / lI;
#pragma unroll
  for (int n = 0; n < 4; ++n) {
    u16x4 pk;
#pragma unroll
    for (int i = 0; i < 4; ++i) pk[i] = f2b(o[n][i] * rl);
    *(u16x4*)&out[(rb + qq) * 1024 + h * 64 + n * 16 + g * 4] = pk;
  }
}

// ---------------- launcher ----------------
extern "C" void kernel_launch(void* const* d_in, const int* in_sizes, int n_in,
                              void* d_out, int out_size, void* d_ws, size_t ws_size,
                              hipStream_t stream) {
  const float* x     = (const float*)d_in[0];
  const float* w_qkv = (const float*)d_in[1];
  const float* w_out = (const float*)d_in[2];

  const size_t n_x   = (size_t)BATCH * T_SEQ * DM;
  const size_t n_wq  = (size_t)3 * DM * DM;
  const size_t n_wo  = (size_t)DM * DM;
  const size_t n_qkv = (size_t)BATCH * T_SEQ * 3 * DM;
  const size_t need  = (n_x + n_wq + n_wo + n_qkv + n_x) * 2;
  if (ws_size < need) return;

  unsigned short* xb  = (unsigned short*)d_ws;
  unsigned short* wqb = xb + n_x;
  unsigned short* wob = wqb + n_wq;
  unsigned short* qkv = wob + n_wo;
  unsigned short* att = qkv + n_qkv;

  cvt_all<<<2048, 256, 0, stream>>>(x, w_qkv, w_out, xb, wqb, wob);

  gemm_bt<0><<<dim3(64, 24), 256, 0, stream>>>(xb, wqb, qkv, BATCH * T_SEQ, 3 * DM, DM);
  attn_kernel<<<dim3(BATCH * NH, T_SEQ / 128), 512, 0, stream>>>(qkv, att);
  gemm_bt<1><<<dim3(64, 8), 256, 0, stream>>>(att, wob, d_out, BATCH * T_SEQ, DM, DM);
}